// Round 1
// baseline (175.702 us; speedup 1.0000x reference)
//
#include <hip/hip_runtime.h>

#define M_TOK 1024
#define NOUT  4096
#define KIN   4096

typedef __attribute__((ext_vector_type(8))) short bf16x8_t;
typedef __attribute__((ext_vector_type(4))) float f32x4_t;

// workspace layout:
//   Bfrag  2 MB @ 0        (bit-bytes in MFMA B-frag order)
//   Wbits  2 MB @ 2 MB     (row-major u64 bitmask, intermediate)
//   Xfrag  8 MB @ 4 MB     (bf16 x in MFMA A-frag order)

// ---- fp32 -> bf16 RNE pack (known-good) ----
__device__ __forceinline__ unsigned pack_bf16(float a, float b) {
  unsigned ua = __float_as_uint(a);
  unsigned ub = __float_as_uint(b);
  ua = (ua + 0x7FFFu + ((ua >> 16) & 1u)) >> 16;
  ub = (ub + 0x7FFFu + ((ub >> 16) & 1u)) >> 16;
  return ua | (ub << 16);
}

// ---- fused prep: blocks 0..1023 = prep_w (ballot bitmask), 1024..3071 = prep_x.
// The two are data-independent; fusing removes one serialized launch and
// overlaps the 64 MB W read with the X convert. Both bodies are the
// known-good kernels from the previous version, unchanged.
__global__ __launch_bounds__(256) void prep_wx(const float* __restrict__ w,
                                               unsigned long long* __restrict__ wbits,
                                               const float4* __restrict__ x4,
                                               uint4* __restrict__ xfrag) {
  if (blockIdx.x < 1024) {
    const int lane = threadIdx.x & 63;
    const int row  = blockIdx.x * 4 + (threadIdx.x >> 6);
    const float* wr = w + (size_t)row * KIN;
    unsigned long long mine = 0;
#pragma unroll 16
    for (int q = 0; q < 64; ++q) {
      float v = wr[q * 64 + lane];
      unsigned long long m = __ballot(v > 0.f);
      if (lane == q) mine = m;
    }
    wbits[(size_t)row * 64 + lane] = mine;
  } else {
    const unsigned t = (blockIdx.x - 1024) * 256 + threadIdx.x;  // 524,288 total
    const int l = t & 63;
    const unsigned f = t >> 6;
    const int m16 = f >> 7, k32 = f & 127;
    const int row = m16 * 16 + (l & 15);
    const int c4  = k32 * 8 + (l >> 4) * 2;
    const float4* p = x4 + (size_t)row * (KIN / 4) + c4;
    float4 a = p[0], b = p[1];
    uint4 o;
    o.x = pack_bf16(a.x, a.y);
    o.y = pack_bf16(a.z, a.w);
    o.z = pack_bf16(b.x, b.y);
    o.w = pack_bf16(b.z, b.w);
    xfrag[t] = o;
  }
}

// ---- prep_w2: shuffle bits to B-frag byte order (known-good, unchanged) ----
__global__ __launch_bounds__(256) void prep_w2(const unsigned long long* __restrict__ wbits,
                                               unsigned short* __restrict__ bfrag) {
  const unsigned t = blockIdx.x * 256 + threadIdx.x;  // 1,048,576 total
  const int l = t & 63, kt = (t >> 6) & 63, n16 = t >> 12;
  const int row = n16 * 16 + (l & 15), quad = l >> 4;
  unsigned long long w64 = wbits[(size_t)row * 64 + kt];
  unsigned b0 = (unsigned)(w64 >> (quad * 8)) & 0xFFu;
  unsigned b1 = (unsigned)(w64 >> (quad * 8 + 32)) & 0xFFu;
  bfrag[t] = (unsigned short)(b0 | (b1 << 8));
}

// ---- GEMM v2: no LDS, no barriers. Block tile 128m x 64n; all 4 waves share
// the SAME 128-row m-band (identical A-frag streams -> L1/MSHR dedup), each
// wave owns one n16 column (wave tile 128m x 16n, acc[8]).
// Expansion amortized over i=8 MFMAs and done mul-free: set bit -> bf16 2.0
// (0x4000, single bit): u32 = ((br<<s1)|(br<<s2)) & 0x40004000 (3 VALU/pair);
// epilogue scale carries the exact x0.5 compensation.
// Swizzle: xcd = bid&7 owns m-band xcd -> A panel (1 MB) + B bits (2 MB) are
// L2-resident per XCD.
__global__ __launch_bounds__(256, 2) void gemm_bin_kernel(
    const unsigned short* __restrict__ Xf,
    const unsigned short* __restrict__ Bf,
    const float* __restrict__ sf,
    float* __restrict__ C) {
  const int tid  = threadIdx.x;
  const int lane = tid & 63;
  const int wave = tid >> 6;
  const int quad = lane >> 4;
  const int l16  = lane & 15;
  const unsigned bid = blockIdx.x;
  const int xcd = bid & 7, idx = bid >> 3;   // idx 0..63
  const int m0  = xcd * 128;                 // 8 m-bands, 1 per XCD
  const int n0  = idx * 64;                  // 64 n-tiles
  const int m16b = m0 >> 4;                  // 8 consecutive m16 tiles (shared by all waves)
  const int n16  = (n0 >> 4) + wave;         // one n16 tile per wave

  const uint4* Xf4 = (const uint4*)Xf;

  f32x4_t acc[8];
#pragma unroll
  for (int i = 0; i < 8; ++i) acc[i] = (f32x4_t){0.f, 0.f, 0.f, 0.f};

  auto loadA = [&](uint4 (&a)[8], int h) {   // h = kt*2 + ks, 0..127
#pragma unroll
    for (int i = 0; i < 8; ++i)
      a[i] = Xf4[((m16b + i) * 128 + h) * 64 + lane];
  };
  auto loadB = [&](int kt) -> unsigned {
    return (unsigned)Bf[(n16 * 64 + kt) * 64 + lane];
  };
  auto computeHalf = [&](uint4 (&a)[8], unsigned br, int ks) {
    union { unsigned u[4]; bf16x8_t v; } ex;
#pragma unroll
    for (int p = 0; p < 4; ++p)
      ex.u[p] = ((br << (14 - 8 * ks - 2 * p)) | (br << (29 - 8 * ks - 2 * p))) & 0x40004000u;
#pragma unroll
    for (int i = 0; i < 8; ++i) {
      union { uint4 q; bf16x8_t v; } av;
      av.q = a[i];
      acc[i] = __builtin_amdgcn_mfma_f32_16x16x32_bf16(av.v, ex.v, acc[i], 0, 0, 0);
    }
  };

  // half-kt double buffer: a0/a1 = 32+32 VGPRs, keeps total well under 256
  uint4 a0[8], a1[8];
  unsigned b0, b1 = 0;
  loadA(a0, 0);
  b0 = loadB(0);
  for (int kt = 0; kt < 64; ++kt) {
    loadA(a1, 2 * kt + 1);
    if (kt + 1 < 64) b1 = loadB(kt + 1);
    computeHalf(a0, b0, 0);
    if (kt + 1 < 64) loadA(a0, 2 * kt + 2);
    computeHalf(a1, b0, 1);
    b0 = b1;
  }

  // epilogue: C/D layout col = lane&15, row = quad*4 + reg.
  // *0.5f compensates the 2.0 bit-encoding (exact: power of two).
  const int n = n0 + wave * 16 + l16;
  const float s = rintf(fmaxf(sf[n], 1.0f)) * 0.5f;
#pragma unroll
  for (int i = 0; i < 8; ++i) {
    const int mr = m0 + i * 16 + quad * 4;
#pragma unroll
    for (int r = 0; r < 4; ++r)
      C[(size_t)(mr + r) * NOUT + n] = acc[i][r] * s;
  }
}

extern "C" void kernel_launch(void* const* d_in, const int* in_sizes, int n_in,
                              void* d_out, int out_size, void* d_ws, size_t ws_size,
                              hipStream_t stream) {
  const float* x  = (const float*)d_in[0];  // [1024][4096]
  const float* w  = (const float*)d_in[1];  // [4096][4096]
  const float* sf = (const float*)d_in[2];  // [4096]
  float* out = (float*)d_out;               // [1024][4096]

  unsigned short*     Bfrag = (unsigned short*)d_ws;                        // 2 MB
  unsigned long long* Wbits = (unsigned long long*)((char*)d_ws + (2u << 20));
  unsigned short*     Xfrag = (unsigned short*)((char*)d_ws + (4u << 20));  // 8 MB

  prep_wx<<<3072, 256, 0, stream>>>(w, Wbits, (const float4*)x, (uint4*)Xfrag);
  prep_w2<<<4096, 256, 0, stream>>>(Wbits, Bfrag);
  gemm_bin_kernel<<<512, 256, 0, stream>>>(Xfrag, Bfrag, sf, out);
}

// Round 2
// 159.091 us; speedup vs baseline: 1.1044x; 1.1044x over previous
//
#include <hip/hip_runtime.h>

#define M_TOK 1024
#define NOUT  4096
#define KIN   4096

typedef __attribute__((ext_vector_type(8))) short bf16x8_t;
typedef __attribute__((ext_vector_type(4))) float f32x4_t;

// workspace layout:
//   Bfrag  2 MB @ 0        (bit-bytes in MFMA B-frag order)
//   (2 MB @ 2 MB unused -- was Wbits intermediate, now fused away)
//   Xfrag  8 MB @ 4 MB     (bf16 x in MFMA A-frag order)

// ---- fp32 -> bf16 RNE pack (known-good) ----
__device__ __forceinline__ unsigned pack_bf16(float a, float b) {
  unsigned ua = __float_as_uint(a);
  unsigned ub = __float_as_uint(b);
  ua = (ua + 0x7FFFu + ((ua >> 16) & 1u)) >> 16;
  ub = (ub + 0x7FFFu + ((ub >> 16) & 1u)) >> 16;
  return ua | (ub << 16);
}

// ---- fused prep: blocks 0..255 = W -> Bfrag directly (ballot bitmask staged
// in LDS, then shuffled to B-frag byte order in-block -- removes the prep_w2
// launch and the Wbits HBM round-trip). Blocks 256..2303 = X -> Xfrag
// (identical to the known-good prep_x). W first: it's the longer stream.
__global__ __launch_bounds__(256) void prep_wx(const float* __restrict__ w,
                                               unsigned short* __restrict__ bfrag,
                                               const float4* __restrict__ x4,
                                               uint4* __restrict__ xfrag) {
  // padded [16][65] u64: shuffle-read lbits[l&15][kt] spreads banks (2r+2kt)%32
  // across the 16 rows; unpadded [16][64] is a 16-way conflict on one bank.
  __shared__ unsigned long long lbits[16][65];
  const int tid  = threadIdx.x;
  const int lane = tid & 63;
  const int wave = tid >> 6;

  if (blockIdx.x < 256) {
    const int n16 = blockIdx.x;            // this block owns output rows n16*16..+15
    // wave handles kt = wave*16 + q, i.e. cols wave*1024 + q*64 + lane
#pragma unroll 1
    for (int rr = 0; rr < 16; ++rr) {
      const float* wr = w + (size_t)(n16 * 16 + rr) * KIN + wave * 1024;
      unsigned long long mine = 0;
#pragma unroll 16
      for (int q = 0; q < 16; ++q) {
        float v = wr[q * 64 + lane];
        unsigned long long m = __ballot(v > 0.f);
        if (lane == q) mine = m;           // lanes 0..15 keep ballots q=0..15
      }
      if (lane < 16) lbits[rr][wave * 16 + lane] = mine;
    }
    __syncthreads();
    // write 4096 ushorts (B-frag order), same formulas as the old prep_w2
#pragma unroll
    for (int it = 0; it < 16; ++it) {
      const int idx = it * 256 + tid;      // = kt*64 + l
      const int l = idx & 63, kt = idx >> 6;
      const unsigned long long w64 = lbits[l & 15][kt];
      const int quad = l >> 4;
      const unsigned b0 = (unsigned)(w64 >> (quad * 8)) & 0xFFu;
      const unsigned b1 = (unsigned)(w64 >> (quad * 8 + 32)) & 0xFFu;
      bfrag[(size_t)n16 * 4096 + idx] = (unsigned short)(b0 | (b1 << 8));
    }
  } else {
    const unsigned t = (blockIdx.x - 256) * 256 + tid;  // 524,288 total
    const int l = t & 63;
    const unsigned f = t >> 6;
    const int m16 = f >> 7, k32 = f & 127;
    const int row = m16 * 16 + (l & 15);
    const int c4  = k32 * 8 + (l >> 4) * 2;
    const float4* p = x4 + (size_t)row * (KIN / 4) + c4;
    float4 a = p[0], b = p[1];
    uint4 o;
    o.x = pack_bf16(a.x, a.y);
    o.y = pack_bf16(a.z, a.w);
    o.z = pack_bf16(b.x, b.y);
    o.w = pack_bf16(b.z, b.w);
    xfrag[t] = o;
  }
}

// ---- GEMM v3: v1's proven tiling (block 64m x 128n, wave 64m x 32n, i=4 j=2,
// 512 blocks = 2/CU, no LDS, no barriers) + two local changes:
//  (1) mul-free expansion verified in v2: set bit -> bf16 2.0 (0x4000);
//      ex = ((br<<s)|(br<<s')) & 0x40004000, x0.5 folded into epilogue scale
//      (exact, power of two). 48 VALU/kt vs 84.
//  (2) 2-kt-deep prefetch: 4 static A/B buffer sets, kt-loop unrolled x4
//      (all buffer indices compile-time -> no scratch). Covers L2 latency
//      jitter that 1-kt double-buffering left exposed.
// Swizzle: xcd = bid&7 owns m-bands {2*xcd, 2*xcd+1} (A band L2-resident/XCD).
__global__ __launch_bounds__(256, 2) void gemm_bin_kernel(
    const unsigned short* __restrict__ Xf,
    const unsigned short* __restrict__ Bf,
    const float* __restrict__ sf,
    float* __restrict__ C) {
  const int tid  = threadIdx.x;
  const int lane = tid & 63;
  const int wave = tid >> 6;
  const int quad = lane >> 4;
  const int l16  = lane & 15;
  const unsigned bid = blockIdx.x;
  const int xcd = bid & 7, idx = bid >> 3;        // idx 0..63
  const int m0 = (xcd * 2 + (idx >> 5)) * 64;     // 16 m-bands, 2 per XCD
  const int n0 = (idx & 31) * 128;                // 32 n-tiles per band
  const int wn = wave * 32;
  const int m16b = m0 >> 4;                       // 4 consecutive m16 tiles (shared)
  const int n16b = (n0 + wn) >> 4;                // 2 consecutive n16 tiles (per wave)

  const uint4* Xf4 = (const uint4*)Xf;

  f32x4_t acc[4][2];
#pragma unroll
  for (int i = 0; i < 4; ++i)
#pragma unroll
    for (int j = 0; j < 2; ++j)
      acc[i][j] = (f32x4_t){0.f, 0.f, 0.f, 0.f};

  uint4 a[4][4][2];        // [buf][i][ks]
  unsigned b[4][2];        // [buf][j]

  auto LOAD = [&](int u, int kt) {
#pragma unroll
    for (int i = 0; i < 4; ++i)
#pragma unroll
      for (int ks = 0; ks < 2; ++ks)
        a[u][i][ks] = Xf4[((size_t)(m16b + i) * 128 + kt * 2 + ks) * 64 + lane];
#pragma unroll
    for (int j = 0; j < 2; ++j)
      b[u][j] = (unsigned)Bf[((n16b + j) * 64 + kt) * 64 + lane];
  };

  auto COMP = [&](int u) {
#pragma unroll
    for (int j = 0; j < 2; ++j)
#pragma unroll
      for (int ks = 0; ks < 2; ++ks) {
        const unsigned br = b[u][j];
        union { unsigned u32[4]; bf16x8_t v; } ex;
#pragma unroll
        for (int p = 0; p < 4; ++p)
          ex.u32[p] = ((br << (14 - 8 * ks - 2 * p)) |
                       (br << (29 - 8 * ks - 2 * p))) & 0x40004000u;
#pragma unroll
        for (int i = 0; i < 4; ++i) {
          union { uint4 q; bf16x8_t v; } av;
          av.q = a[u][i][ks];
          acc[i][j] = __builtin_amdgcn_mfma_f32_16x16x32_bf16(av.v, ex.v, acc[i][j], 0, 0, 0);
        }
      }
  };

  LOAD(0, 0);
  LOAD(1, 1);
  for (int kt = 0; kt < 64; kt += 4) {
    LOAD(2, kt + 2);
    COMP(0);
    LOAD(3, kt + 3);
    COMP(1);
    if (kt + 4 < 64) LOAD(0, kt + 4);
    COMP(2);
    if (kt + 5 < 64) LOAD(1, kt + 5);
    COMP(3);
  }

  // epilogue: C/D layout col = lane&15, row = quad*4 + reg.
  // *0.5f compensates the 2.0 bit-encoding (exact).
#pragma unroll
  for (int j = 0; j < 2; ++j) {
    const int n = n0 + wn + j * 16 + l16;
    const float s = rintf(fmaxf(sf[n], 1.0f)) * 0.5f;
#pragma unroll
    for (int i = 0; i < 4; ++i) {
      const int mr = m0 + i * 16 + quad * 4;
#pragma unroll
      for (int r = 0; r < 4; ++r)
        C[(size_t)(mr + r) * NOUT + n] = acc[i][j][r] * s;
    }
  }
}

extern "C" void kernel_launch(void* const* d_in, const int* in_sizes, int n_in,
                              void* d_out, int out_size, void* d_ws, size_t ws_size,
                              hipStream_t stream) {
  const float* x  = (const float*)d_in[0];  // [1024][4096]
  const float* w  = (const float*)d_in[1];  // [4096][4096]
  const float* sf = (const float*)d_in[2];  // [4096]
  float* out = (float*)d_out;               // [1024][4096]

  unsigned short* Bfrag = (unsigned short*)d_ws;                        // 2 MB
  unsigned short* Xfrag = (unsigned short*)((char*)d_ws + (4u << 20));  // 8 MB

  prep_wx<<<2304, 256, 0, stream>>>(w, Bfrag, (const float4*)x, (uint4*)Xfrag);
  gemm_bin_kernel<<<512, 256, 0, stream>>>(Xfrag, Bfrag, sf, out);
}

// Round 3
// 154.895 us; speedup vs baseline: 1.1343x; 1.0271x over previous
//
#include <hip/hip_runtime.h>

#define M_TOK 1024
#define NOUT  4096
#define KIN   4096

typedef __attribute__((ext_vector_type(8))) short bf16x8_t;
typedef __attribute__((ext_vector_type(4))) float f32x4_t;

// workspace layout:
//   Bfrag32  4 MB @ 0      (bit-SPREAD u32 per (n16,kt,lane): bit 2e at 14-2e,
//                           bit 2e+1 at 30-2e -> GEMM expansion = shl+and)
//   Xfrag    8 MB @ 4 MB   (bf16 x in MFMA A-frag order)

// ---- fp32 -> bf16 RNE pack (known-good) ----
__device__ __forceinline__ unsigned pack_bf16(float a, float b) {
  unsigned ua = __float_as_uint(a);
  unsigned ub = __float_as_uint(b);
  ua = (ua + 0x7FFFu + ((ua >> 16) & 1u)) >> 16;
  ub = (ub + 0x7FFFu + ((ub >> 16) & 1u)) >> 16;
  return ua | (ub << 16);
}

// spread 16 bits so that ex_{ks,p} = (U << 2*(ks*4+p)) & 0x40004000:
//   br[2e]   -> U[14-2e]   (low bf16 half, value 2.0 = 0x4000)
//   br[2e+1] -> U[30-2e]   (high bf16 half)
__device__ __forceinline__ unsigned spread_bits(unsigned br) {
  unsigned U = 0;
#pragma unroll
  for (int e = 0; e < 8; ++e)
    U |= (((br >> (2 * e)) & 1u) << (14 - 2 * e)) |
         (((br >> (2 * e + 1)) & 1u) << (30 - 2 * e));
  return U;
}

// ---- fused prep: blocks 0..1023 = W -> Bfrag32 (4 blocks per n16, each does a
// quarter of K; 4x the parallelism of v3's W-part). Blocks 1024..3071 = X ->
// Xfrag (known-good, unchanged). Ballot + LDS-shuffle formulas verbatim from
// the verified v3 path; only the output encoding changed (spread u32).
__global__ __launch_bounds__(256) void prep_wx(const float* __restrict__ w,
                                               unsigned* __restrict__ bfrag32,
                                               const float4* __restrict__ x4,
                                               uint4* __restrict__ xfrag) {
  __shared__ unsigned long long lbits[16][17];  // [row][ktl], pad kills conflicts
  const int tid  = threadIdx.x;
  const int lane = tid & 63;
  const int wave = tid >> 6;

  if (blockIdx.x < 1024) {
    const int n16 = blockIdx.x >> 2;   // output row group (16 rows)
    const int kq  = blockIdx.x & 3;    // quarter of K: cols [kq*1024, +1024)
    // wave w covers ktl = w*4+q (q=0..3), i.e. cols w*256 + q*64 + lane
#pragma unroll 1
    for (int rr = 0; rr < 16; ++rr) {
      const float* wr = w + (size_t)(n16 * 16 + rr) * KIN + kq * 1024 + wave * 256;
      unsigned long long mine = 0;
#pragma unroll
      for (int q = 0; q < 4; ++q) {
        float v = wr[q * 64 + lane];
        unsigned long long m = __ballot(v > 0.f);
        if (lane == q) mine = m;       // lanes 0..3 keep ballots q=0..3
      }
      if (lane < 4) lbits[rr][wave * 4 + lane] = mine;
    }
    __syncthreads();
    // 1024 u32 outputs per block: idx = ktl*64 + l
#pragma unroll
    for (int it = 0; it < 4; ++it) {
      const int idx = it * 256 + tid;
      const int l = idx & 63, ktl = idx >> 6;          // ktl 0..15
      const unsigned long long w64 = lbits[l & 15][ktl];
      const int quad = l >> 4;
      const unsigned b0 = (unsigned)(w64 >> (quad * 8)) & 0xFFu;
      const unsigned b1 = (unsigned)(w64 >> (quad * 8 + 32)) & 0xFFu;
      const unsigned br = b0 | (b1 << 8);
      bfrag32[((size_t)n16 * 64 + kq * 16 + ktl) * 64 + l] = spread_bits(br);
    }
  } else {
    const unsigned t = (blockIdx.x - 1024) * 256 + tid;  // 524,288 total
    const int l = t & 63;
    const unsigned f = t >> 6;
    const int m16 = f >> 7, k32 = f & 127;
    const int row = m16 * 16 + (l & 15);
    const int c4  = k32 * 8 + (l >> 4) * 2;
    const float4* p = x4 + (size_t)row * (KIN / 4) + c4;
    float4 a = p[0], b = p[1];
    uint4 o;
    o.x = pack_bf16(a.x, a.y);
    o.y = pack_bf16(a.z, a.w);
    o.z = pack_bf16(b.x, b.y);
    o.w = pack_bf16(b.z, b.w);
    xfrag[t] = o;
  }
}

// ---- GEMM v4: occupancy fix. 1024 blocks x 256 thr = 4 blocks/CU = 16
// waves/CU = 4 waves/SIMD (v1 had 2/SIMD -> latency-bound at MfmaUtil 28%).
// Block tile 32m x 128n, wave tile 32m x 32n (i=2, j=2): per kt = 4 A-dwordx4
// + 2 B-dword feeding 8 MFMAs -- per-CU L1 data demand per MFMA identical to
// v1. Same proven 2-deep prefetch schedule (v3's 4-deep regressed: MSHR
// thrash). Expansion via pre-spread B: 2 VALU per ex-word (shl+and).
// Swizzle: xcd = bid&7 owns 4 m-tiles (128 rows, 1 MB A panel L2-resident).
__global__ __launch_bounds__(256, 4) void gemm_bin_kernel(
    const unsigned short* __restrict__ Xf,
    const unsigned* __restrict__ Bf32,
    const float* __restrict__ sf,
    float* __restrict__ C) {
  const int tid  = threadIdx.x;
  const int lane = tid & 63;
  const int wave = tid >> 6;
  const int quad = lane >> 4;
  const int l16  = lane & 15;
  const unsigned bid = blockIdx.x;
  const int xcd = bid & 7, idx = bid >> 3;        // idx 0..127
  const int m0 = (xcd * 4 + (idx >> 5)) * 32;     // 32 m-tiles, 4 per XCD
  const int n0 = (idx & 31) * 128;                // 32 n-slabs
  const int m16b = m0 >> 4;                       // 2 consecutive m16 tiles
  const int n16b = (n0 + wave * 32) >> 4;         // 2 consecutive n16 per wave

  const uint4* Xf4 = (const uint4*)Xf;

  f32x4_t acc[2][2];
#pragma unroll
  for (int i = 0; i < 2; ++i)
#pragma unroll
    for (int j = 0; j < 2; ++j)
      acc[i][j] = (f32x4_t){0.f, 0.f, 0.f, 0.f};

  uint4 a[2][2][2];      // [buf][i][ks]
  unsigned b[2][2];      // [buf][j]

  auto LOAD = [&](int u, int kt) {
#pragma unroll
    for (int i = 0; i < 2; ++i)
#pragma unroll
      for (int ks = 0; ks < 2; ++ks)
        a[u][i][ks] = Xf4[((size_t)(m16b + i) * 128 + kt * 2 + ks) * 64 + lane];
#pragma unroll
    for (int j = 0; j < 2; ++j)
      b[u][j] = Bf32[((n16b + j) * 64 + kt) * 64 + lane];
  };

  auto COMP = [&](int u) {
#pragma unroll
    for (int j = 0; j < 2; ++j) {
      const unsigned U = b[u][j];
#pragma unroll
      for (int ks = 0; ks < 2; ++ks) {
        union { unsigned u32[4]; bf16x8_t v; } ex;
#pragma unroll
        for (int p = 0; p < 4; ++p)
          ex.u32[p] = (U << (2 * (ks * 4 + p))) & 0x40004000u;
#pragma unroll
        for (int i = 0; i < 2; ++i) {
          union { uint4 q; bf16x8_t v; } av;
          av.q = a[u][i][ks];
          acc[i][j] = __builtin_amdgcn_mfma_f32_16x16x32_bf16(av.v, ex.v, acc[i][j], 0, 0, 0);
        }
      }
    }
  };

  LOAD(0, 0);
  for (int kt = 0; kt < 64; kt += 2) {
    LOAD(1, kt + 1);
    COMP(0);
    if (kt + 2 < 64) LOAD(0, kt + 2);
    COMP(1);
  }

  // epilogue: C/D layout col = lane&15, row = quad*4 + reg.
  // *0.5f compensates the 2.0 bit-encoding (exact, power of two).
#pragma unroll
  for (int j = 0; j < 2; ++j) {
    const int n = n0 + wave * 32 + j * 16 + l16;
    const float s = rintf(fmaxf(sf[n], 1.0f)) * 0.5f;
#pragma unroll
    for (int i = 0; i < 2; ++i) {
      const int mr = m0 + i * 16 + quad * 4;
#pragma unroll
      for (int r = 0; r < 4; ++r)
        C[(size_t)(mr + r) * NOUT + n] = acc[i][j][r] * s;
    }
  }
}

extern "C" void kernel_launch(void* const* d_in, const int* in_sizes, int n_in,
                              void* d_out, int out_size, void* d_ws, size_t ws_size,
                              hipStream_t stream) {
  const float* x  = (const float*)d_in[0];  // [1024][4096]
  const float* w  = (const float*)d_in[1];  // [4096][4096]
  const float* sf = (const float*)d_in[2];  // [4096]
  float* out = (float*)d_out;               // [1024][4096]

  unsigned*       Bfrag32 = (unsigned*)d_ws;                              // 4 MB
  unsigned short* Xfrag   = (unsigned short*)((char*)d_ws + (4u << 20));  // 8 MB

  prep_wx<<<3072, 256, 0, stream>>>(w, Bfrag32, (const float4*)x, (uint4*)Xfrag);
  gemm_bin_kernel<<<1024, 256, 0, stream>>>(Xfrag, Bfrag32, sf, out);
}

// Round 4
// 149.712 us; speedup vs baseline: 1.1736x; 1.0346x over previous
//
#include <hip/hip_runtime.h>

#define M_TOK 1024
#define NOUT  4096
#define KIN   4096

typedef __attribute__((ext_vector_type(8))) short bf16x8_t;
typedef __attribute__((ext_vector_type(4))) float f32x4_t;

// workspace layout:
//   Bfrag  2 MB @ 0        (bit-bytes in MFMA B-frag order, u16 per (n16,kt,lane))
//   Xfrag  8 MB @ 4 MB     (bf16 x in MFMA A-frag order)
// B kept at u16/2MB deliberately: per-XCD L2 working set = A band (1 MB) +
// B (2 MB) = 3 MB < 4 MB. v4's 4 MB spread-B blew L2 (FETCH 12.4 -> 28.4 MB).

// ---- fp32 -> bf16 RNE pack (known-good) ----
__device__ __forceinline__ unsigned pack_bf16(float a, float b) {
  unsigned ua = __float_as_uint(a);
  unsigned ub = __float_as_uint(b);
  ua = (ua + 0x7FFFu + ((ua >> 16) & 1u)) >> 16;
  ub = (ub + 0x7FFFu + ((ub >> 16) & 1u)) >> 16;
  return ua | (ub << 16);
}

// ---- fused prep: blocks 0..1023 = W -> Bfrag u16 (4 blocks per n16, quarter-K
// each; ballot + LDS shuffle formulas verified in v0/v3). Blocks 1024..3071 =
// X -> Xfrag (known-good, unchanged).
__global__ __launch_bounds__(256) void prep_wx(const float* __restrict__ w,
                                               unsigned short* __restrict__ bfrag,
                                               const float4* __restrict__ x4,
                                               uint4* __restrict__ xfrag) {
  __shared__ unsigned long long lbits[16][17];  // [row][ktl], pad kills conflicts
  const int tid  = threadIdx.x;
  const int lane = tid & 63;
  const int wave = tid >> 6;

  if (blockIdx.x < 1024) {
    const int n16 = blockIdx.x >> 2;   // output row group (16 rows)
    const int kq  = blockIdx.x & 3;    // quarter of K: cols [kq*1024, +1024)
#pragma unroll 1
    for (int rr = 0; rr < 16; ++rr) {
      const float* wr = w + (size_t)(n16 * 16 + rr) * KIN + kq * 1024 + wave * 256;
      unsigned long long mine = 0;
#pragma unroll
      for (int q = 0; q < 4; ++q) {
        float v = wr[q * 64 + lane];
        unsigned long long m = __ballot(v > 0.f);
        if (lane == q) mine = m;       // lanes 0..3 keep ballots q=0..3
      }
      if (lane < 4) lbits[rr][wave * 4 + lane] = mine;
    }
    __syncthreads();
    // 1024 u16 outputs per block: idx = ktl*64 + l  (kt = kq*16 + ktl)
#pragma unroll
    for (int it = 0; it < 4; ++it) {
      const int idx = it * 256 + tid;
      const int l = idx & 63, ktl = idx >> 6;          // ktl 0..15
      const unsigned long long w64 = lbits[l & 15][ktl];
      const int quad = l >> 4;
      const unsigned b0 = (unsigned)(w64 >> (quad * 8)) & 0xFFu;
      const unsigned b1 = (unsigned)(w64 >> (quad * 8 + 32)) & 0xFFu;
      bfrag[((size_t)n16 * 64 + kq * 16 + ktl) * 64 + l] =
          (unsigned short)(b0 | (b1 << 8));
    }
  } else {
    const unsigned t = (blockIdx.x - 1024) * 256 + tid;  // 524,288 total
    const int l = t & 63;
    const unsigned f = t >> 6;
    const int m16 = f >> 7, k32 = f & 127;
    const int row = m16 * 16 + (l & 15);
    const int c4  = k32 * 8 + (l >> 4) * 2;
    const float4* p = x4 + (size_t)row * (KIN / 4) + c4;
    float4 a = p[0], b = p[1];
    uint4 o;
    o.x = pack_bf16(a.x, a.y);
    o.y = pack_bf16(a.z, a.w);
    o.z = pack_bf16(b.x, b.y);
    o.w = pack_bf16(b.z, b.w);
    xfrag[t] = o;
  }
}

// ---- GEMM v5: EXACTLY the v1 schedule (best measured: 45.2 us, 761 TF):
// block 64m x 128n, wave 64m x 32n (i=4, j=2), 2-deep prefetch, 512 blocks =
// 2/CU, no LDS, no barriers, m-band shared by all 4 waves (L1 dedup), XCD
// swizzle (A band + B = 3 MB L2-resident per XCD).
// ONLY change vs v1: expansion is the v2-verified 3-op form -- set bit ->
// bf16 2.0 (0x4000): ex = ((br<<s1)|(br<<s2)) & 0x40004000, x0.5 folded into
// the epilogue scale (exact, power of two). ~68 vs ~100 VALU per kt.
__global__ __launch_bounds__(256, 2) void gemm_bin_kernel(
    const unsigned short* __restrict__ Xf,
    const unsigned short* __restrict__ Bf,
    const float* __restrict__ sf,
    float* __restrict__ C) {
  const int tid  = threadIdx.x;
  const int lane = tid & 63;
  const int wave = tid >> 6;
  const int quad = lane >> 4;
  const int l16  = lane & 15;
  const unsigned bid = blockIdx.x;
  const int xcd = bid & 7, idx = bid >> 3;        // idx 0..63
  const int m0 = (xcd * 2 + (idx >> 5)) * 64;     // 16 m-bands, 2 per XCD
  const int n0 = (idx & 31) * 128;                // 32 n-tiles per band
  const int wn = wave * 32;
  const int m16b = m0 >> 4;                       // 4 consecutive m16 tiles (shared)
  const int n16b = (n0 + wn) >> 4;                // 2 consecutive n16 tiles (per wave)

  const uint4* Xf4 = (const uint4*)Xf;

  f32x4_t acc[4][2];
#pragma unroll
  for (int i = 0; i < 4; ++i)
#pragma unroll
    for (int j = 0; j < 2; ++j)
      acc[i][j] = (f32x4_t){0.f, 0.f, 0.f, 0.f};

  uint4 a[2][4][2];      // [buf][i][ks]
  unsigned b[2][2];      // [buf][j]

  auto LOAD = [&](int u, int kt) {
#pragma unroll
    for (int i = 0; i < 4; ++i)
#pragma unroll
      for (int ks = 0; ks < 2; ++ks)
        a[u][i][ks] = Xf4[((size_t)(m16b + i) * 128 + kt * 2 + ks) * 64 + lane];
#pragma unroll
    for (int j = 0; j < 2; ++j)
      b[u][j] = (unsigned)Bf[((n16b + j) * 64 + kt) * 64 + lane];
  };

  auto COMP = [&](int u) {
#pragma unroll
    for (int j = 0; j < 2; ++j)
#pragma unroll
      for (int ks = 0; ks < 2; ++ks) {
        const unsigned br = b[u][j];   // 16-bit, zero-extended: no garbage bits
        union { unsigned u32[4]; bf16x8_t v; } ex;
#pragma unroll
        for (int p = 0; p < 4; ++p)
          ex.u32[p] = ((br << (14 - 8 * ks - 2 * p)) |
                       (br << (29 - 8 * ks - 2 * p))) & 0x40004000u;
#pragma unroll
        for (int i = 0; i < 4; ++i) {
          union { uint4 q; bf16x8_t v; } av;
          av.q = a[u][i][ks];
          acc[i][j] = __builtin_amdgcn_mfma_f32_16x16x32_bf16(av.v, ex.v, acc[i][j], 0, 0, 0);
        }
      }
  };

  LOAD(0, 0);
  for (int kt = 0; kt < 64; kt += 2) {
    LOAD(1, kt + 1);
    COMP(0);
    if (kt + 2 < 64) LOAD(0, kt + 2);
    COMP(1);
  }

  // epilogue: C/D layout col = lane&15, row = quad*4 + reg.
  // *0.5f compensates the 2.0 bit-encoding (exact, power of two).
#pragma unroll
  for (int j = 0; j < 2; ++j) {
    const int n = n0 + wn + j * 16 + l16;
    const float s = rintf(fmaxf(sf[n], 1.0f)) * 0.5f;
#pragma unroll
    for (int i = 0; i < 4; ++i) {
      const int mr = m0 + i * 16 + quad * 4;
#pragma unroll
      for (int r = 0; r < 4; ++r)
        C[(size_t)(mr + r) * NOUT + n] = acc[i][j][r] * s;
    }
  }
}

extern "C" void kernel_launch(void* const* d_in, const int* in_sizes, int n_in,
                              void* d_out, int out_size, void* d_ws, size_t ws_size,
                              hipStream_t stream) {
  const float* x  = (const float*)d_in[0];  // [1024][4096]
  const float* w  = (const float*)d_in[1];  // [4096][4096]
  const float* sf = (const float*)d_in[2];  // [4096]
  float* out = (float*)d_out;               // [1024][4096]

  unsigned short* Bfrag = (unsigned short*)d_ws;                        // 2 MB
  unsigned short* Xfrag = (unsigned short*)((char*)d_ws + (4u << 20));  // 8 MB

  prep_wx<<<3072, 256, 0, stream>>>(w, Bfrag, (const float4*)x, (uint4*)Xfrag);
  gemm_bin_kernel<<<512, 256, 0, stream>>>(Xfrag, Bfrag, sf, out);
}

// Round 5
// 145.382 us; speedup vs baseline: 1.2086x; 1.0298x over previous
//
#include <hip/hip_runtime.h>

#define M_TOK 1024
#define NOUT  4096
#define KIN   4096

typedef __attribute__((ext_vector_type(8))) short bf16x8_t;
typedef __attribute__((ext_vector_type(4))) float f32x4_t;

// workspace layout:
//   Bfrag  2 MB @ 0        (bit-bytes in MFMA B-frag order, u16 per (n16,kt,l))
//   Xfrag  8 MB @ 4 MB     (bf16 x in MFMA A-frag order)
// B kept at u16/2MB: per-XCD L2 working set = A band (1MB) + B (2MB) = 3MB < 4MB.

// ---- fp32 -> bf16 RNE pack (known-good) ----
__device__ __forceinline__ unsigned pack_bf16(float a, float b) {
  unsigned ua = __float_as_uint(a);
  unsigned ub = __float_as_uint(b);
  ua = (ua + 0x7FFFu + ((ua >> 16) & 1u)) >> 16;
  ub = (ub + 0x7FFFu + ((ub >> 16) & 1u)) >> 16;
  return ua | (ub << 16);
}

__device__ __forceinline__ unsigned bits8(float4 a, float4 b) {
  return  (unsigned)(a.x > 0.f)        | ((unsigned)(a.y > 0.f) << 1) |
         ((unsigned)(a.z > 0.f) << 2)  | ((unsigned)(a.w > 0.f) << 3) |
         ((unsigned)(b.x > 0.f) << 4)  | ((unsigned)(b.y > 0.f) << 5) |
         ((unsigned)(b.z > 0.f) << 6)  | ((unsigned)(b.w > 0.f) << 7);
}

// ---- prep v6: PURE STREAMING. No ballot, no LDS, no syncthreads.
// Blocks 0..4095 = W -> Bfrag: thread t emits output u16 t directly.
//   t -> (l16 = t&15, quad = (t>>4)&3, kt = (t>>6)&63, n16 = t>>12), row
//   n = n16*16+l16; b0 = bits of W[n][kt*64+quad*8 .. +8), b1 = same +32
//   (exact prep_w2 semantics, verified rounds 0-5). 4x float4 loads per
//   thread; every 64B line fully consumed; u16 stores fully coalesced.
// Blocks 4096..6143 = X -> Xfrag (known-good, unchanged).
__global__ __launch_bounds__(256) void prep_wx(const float4* __restrict__ w4,
                                               unsigned short* __restrict__ bfrag,
                                               const float4* __restrict__ x4,
                                               uint4* __restrict__ xfrag) {
  const unsigned bb = blockIdx.x;
  if (bb < 4096) {
    const unsigned t = bb * 256 + threadIdx.x;        // 1,048,576 outputs
    const int l16 = t & 15, quad = (t >> 4) & 3;
    const int kt = (t >> 6) & 63, n16 = t >> 12;
    const int n = n16 * 16 + l16;
    // float4 index of col c = c/4; c0 = kt*64 + quad*8 -> kt*16 + quad*2
    const float4* p = w4 + (size_t)n * (KIN / 4) + kt * 16 + quad * 2;
    float4 f0 = p[0], f1 = p[1];      // cols c0 .. c0+7
    float4 f2 = p[8], f3 = p[9];      // cols c0+32 .. c0+39
    const unsigned b0 = bits8(f0, f1);
    const unsigned b1 = bits8(f2, f3);
    bfrag[t] = (unsigned short)(b0 | (b1 << 8));
  } else {
    const unsigned t = (bb - 4096) * 256 + threadIdx.x;  // 524,288 total
    const int l = t & 63;
    const unsigned f = t >> 6;
    const int m16 = f >> 7, k32 = f & 127;
    const int row = m16 * 16 + (l & 15);
    const int c4  = k32 * 8 + (l >> 4) * 2;
    const float4* p = x4 + (size_t)row * (KIN / 4) + c4;
    float4 a = p[0], b = p[1];
    uint4 o;
    o.x = pack_bf16(a.x, a.y);
    o.y = pack_bf16(a.z, a.w);
    o.z = pack_bf16(b.x, b.y);
    o.w = pack_bf16(b.z, b.w);
    xfrag[t] = o;
  }
}

// ---- GEMM v6: the empirical best (v1/round-0, 45.0-45.2 us x3): block
// 64m x 128n, wave 64m x 32n (i=4, j=2), 2-deep prefetch, 512 blocks = 2/CU,
// no LDS, no barriers, m-band shared by 4 waves (L1 dedup), XCD swizzle
// (A band 1MB + B 2MB L2-resident per XCD). COMP/epilogue are v1's verbatim
// (mul-based 1.0-encoding) -- v5's 3-op form cut VALUBusy 40->33 but did NOT
// cut time (latency-bound), so keep the thrice-measured winner.
__global__ __launch_bounds__(256, 2) void gemm_bin_kernel(
    const unsigned short* __restrict__ Xf,
    const unsigned short* __restrict__ Bf,
    const float* __restrict__ sf,
    float* __restrict__ C) {
  const int tid  = threadIdx.x;
  const int lane = tid & 63;
  const int wave = tid >> 6;
  const int quad = lane >> 4;
  const int l16  = lane & 15;
  const unsigned bid = blockIdx.x;
  const int xcd = bid & 7, idx = bid >> 3;        // idx 0..63
  const int m0 = (xcd * 2 + (idx >> 5)) * 64;     // 16 m-bands, 2 per XCD
  const int n0 = (idx & 31) * 128;                // 32 n-tiles per band
  const int wn = wave * 32;
  const int m16b = m0 >> 4;                       // 4 consecutive m16 tiles (shared)
  const int n16b = (n0 + wn) >> 4;                // 2 consecutive n16 tiles (per wave)

  const uint4* Xf4 = (const uint4*)Xf;

  f32x4_t acc[4][2];
#pragma unroll
  for (int i = 0; i < 4; ++i)
#pragma unroll
    for (int j = 0; j < 2; ++j)
      acc[i][j] = (f32x4_t){0.f, 0.f, 0.f, 0.f};

  uint4 a[2][4][2];      // [buf][i][ks]
  unsigned b[2][2];      // [buf][j]

  auto LOAD = [&](int u, int kt) {
#pragma unroll
    for (int i = 0; i < 4; ++i)
#pragma unroll
      for (int ks = 0; ks < 2; ++ks)
        a[u][i][ks] = Xf4[((size_t)(m16b + i) * 128 + kt * 2 + ks) * 64 + lane];
#pragma unroll
    for (int j = 0; j < 2; ++j)
      b[u][j] = (unsigned)Bf[((n16b + j) * 64 + kt) * 64 + lane];
  };

  auto COMP = [&](int u) {
#pragma unroll
    for (int j = 0; j < 2; ++j)
#pragma unroll
      for (int ks = 0; ks < 2; ++ks) {
        unsigned byte = (b[u][j] >> (ks * 8)) & 0xFFu;
        union { unsigned u32[4]; bf16x8_t v; } ex;
#pragma unroll
        for (int p = 0; p < 4; ++p) {
          unsigned tt = (byte >> (2 * p)) & 3u;
          ex.u32[p] = ((tt | (tt << 15)) & 0x10001u) * 0x3F80u;
        }
#pragma unroll
        for (int i = 0; i < 4; ++i) {
          union { uint4 q; bf16x8_t v; } av;
          av.q = a[u][i][ks];
          acc[i][j] = __builtin_amdgcn_mfma_f32_16x16x32_bf16(av.v, ex.v, acc[i][j], 0, 0, 0);
        }
      }
  };

  LOAD(0, 0);
  for (int kt = 0; kt < 64; kt += 2) {
    LOAD(1, kt + 1);
    COMP(0);
    if (kt + 2 < 64) LOAD(0, kt + 2);
    COMP(1);
  }

  // epilogue: C/D layout col = lane&15, row = quad*4 + reg (v1 verbatim)
#pragma unroll
  for (int j = 0; j < 2; ++j) {
    const int n = n0 + wn + j * 16 + l16;
    const float s = rintf(fmaxf(sf[n], 1.0f));
#pragma unroll
    for (int i = 0; i < 4; ++i) {
      const int mr = m0 + i * 16 + quad * 4;
#pragma unroll
      for (int r = 0; r < 4; ++r)
        C[(size_t)(mr + r) * NOUT + n] = acc[i][j][r] * s;
    }
  }
}

extern "C" void kernel_launch(void* const* d_in, const int* in_sizes, int n_in,
                              void* d_out, int out_size, void* d_ws, size_t ws_size,
                              hipStream_t stream) {
  const float* x  = (const float*)d_in[0];  // [1024][4096]
  const float* w  = (const float*)d_in[1];  // [4096][4096]
  const float* sf = (const float*)d_in[2];  // [4096]
  float* out = (float*)d_out;               // [1024][4096]

  unsigned short* Bfrag = (unsigned short*)d_ws;                        // 2 MB
  unsigned short* Xfrag = (unsigned short*)((char*)d_ws + (4u << 20));  // 8 MB

  prep_wx<<<6144, 256, 0, stream>>>((const float4*)w, Bfrag, (const float4*)x,
                                    (uint4*)Xfrag);
  gemm_bin_kernel<<<512, 256, 0, stream>>>(Xfrag, Bfrag, sf, out);
}

// Round 7
// 145.135 us; speedup vs baseline: 1.2106x; 1.0017x over previous
//
#include <hip/hip_runtime.h>

#define M_TOK 1024
#define NOUT  4096
#define KIN   4096

typedef __attribute__((ext_vector_type(8))) short bf16x8_t;
typedef __attribute__((ext_vector_type(4))) float f32x4_t;

// workspace layout:
//   Bfrag  2 MB @ 0        (bit-bytes in MFMA B-frag order, u16 per (n16,kt,l))
//   Xfrag  8 MB @ 4 MB     (bf16 x in MFMA A-frag order)
// B kept at u16/2MB: per-XCD L2 working set = A band (1MB) + B (2MB) = 3MB < 4MB.

// ---- fp32 -> bf16 RNE pack (known-good) ----
__device__ __forceinline__ unsigned pack_bf16(float a, float b) {
  unsigned ua = __float_as_uint(a);
  unsigned ub = __float_as_uint(b);
  ua = (ua + 0x7FFFu + ((ua >> 16) & 1u)) >> 16;
  ub = (ub + 0x7FFFu + ((ub >> 16) & 1u)) >> 16;
  return ua | (ub << 16);
}

__device__ __forceinline__ unsigned bits8(float4 a, float4 b) {
  return  (unsigned)(a.x > 0.f)        | ((unsigned)(a.y > 0.f) << 1) |
         ((unsigned)(a.z > 0.f) << 2)  | ((unsigned)(a.w > 0.f) << 3) |
         ((unsigned)(b.x > 0.f) << 4)  | ((unsigned)(b.y > 0.f) << 5) |
         ((unsigned)(b.z > 0.f) << 6)  | ((unsigned)(b.w > 0.f) << 7);
}

// ---- prep v6 (verified best): pure streaming, no ballot/LDS/sync.
// Blocks 0..4095 = W -> Bfrag (thread t emits u16 t; exact prep_w2 semantics).
// Blocks 4096..6143 = X -> Xfrag (known-good).
__global__ __launch_bounds__(256) void prep_wx(const float4* __restrict__ w4,
                                               unsigned short* __restrict__ bfrag,
                                               const float4* __restrict__ x4,
                                               uint4* __restrict__ xfrag) {
  const unsigned bb = blockIdx.x;
  if (bb < 4096) {
    const unsigned t = bb * 256 + threadIdx.x;        // 1,048,576 outputs
    const int l16 = t & 15, quad = (t >> 4) & 3;
    const int kt = (t >> 6) & 63, n16 = t >> 12;
    const int n = n16 * 16 + l16;
    const float4* p = w4 + (size_t)n * (KIN / 4) + kt * 16 + quad * 2;
    float4 f0 = p[0], f1 = p[1];      // cols c0 .. c0+7
    float4 f2 = p[8], f3 = p[9];      // cols c0+32 .. c0+39
    const unsigned b0 = bits8(f0, f1);
    const unsigned b1 = bits8(f2, f3);
    bfrag[t] = (unsigned short)(b0 | (b1 << 8));
  } else {
    const unsigned t = (bb - 4096) * 256 + threadIdx.x;  // 524,288 total
    const int l = t & 63;
    const unsigned f = t >> 6;
    const int m16 = f >> 7, k32 = f & 127;
    const int row = m16 * 16 + (l & 15);
    const int c4  = k32 * 8 + (l >> 4) * 2;
    const float4* p = x4 + (size_t)row * (KIN / 4) + c4;
    float4 a = p[0], b = p[1];
    uint4 o;
    o.x = pack_bf16(a.x, a.y);
    o.y = pack_bf16(a.z, a.w);
    o.z = pack_bf16(b.x, b.y);
    o.w = pack_bf16(b.z, b.w);
    xfrag[t] = o;
  }
}

// ---- GEMM v7: in-block K-split. Same 64m x 128n block tile, same wave tile
// (64x32, i=4 j=2), same 2-deep prefetch, same v1 COMP, same XCD swizzle and
// L2 working set -- but 512 threads/block: waves 0-3 compute K [0,2048),
// waves 4-7 K [2048,4096) for the SAME four sub-tiles. Total waves double:
// 4096 waves / 1024 SIMDs = 4 waves/SIMD (was 2) at IDENTICAL per-wave
// amortization -- attacks the measured latency-bound regime (v5 showed VALU
// cuts buy nothing; occupancy is the lever; tiling pinned waves at 2/SIMD).
// Reduction: one __syncthreads + 32 KB LDS pairwise add (2-way f32 add is
// order-independent -> deterministic). Waves 0-3 scale+store.
__global__ __launch_bounds__(512, 4) void gemm_bin_kernel(
    const unsigned short* __restrict__ Xf,
    const unsigned short* __restrict__ Bf,
    const float* __restrict__ sf,
    float* __restrict__ C) {
  __shared__ f32x4_t red[4][8][64];               // 32 KB
  const int tid  = threadIdx.x;
  const int lane = tid & 63;
  const int wave = tid >> 6;                      // 0..7
  const int wsub = wave & 3;                      // n-quadrant within block
  const int kh   = wave >> 2;                     // k-half
  const int quad = lane >> 4;
  const int l16  = lane & 15;
  const unsigned bid = blockIdx.x;
  const int xcd = bid & 7, idx = bid >> 3;        // idx 0..63
  const int m0 = (xcd * 2 + (idx >> 5)) * 64;     // 16 m-bands, 2 per XCD
  const int n0 = (idx & 31) * 128;                // 32 n-tiles per band
  const int wn = wsub * 32;
  const int m16b = m0 >> 4;                       // 4 m16 tiles (shared by waves)
  const int n16b = (n0 + wn) >> 4;                // 2 n16 tiles (per wave pair)

  const uint4* Xf4 = (const uint4*)Xf;

  f32x4_t acc[4][2];
#pragma unroll
  for (int i = 0; i < 4; ++i)
#pragma unroll
    for (int j = 0; j < 2; ++j)
      acc[i][j] = (f32x4_t){0.f, 0.f, 0.f, 0.f};

  uint4 a[2][4][2];      // [buf][i][ks]
  unsigned b[2][2];      // [buf][j]

  auto LOAD = [&](int u, int ktl) {
    const int kt = kh * 32 + ktl;                 // global k-tile 0..63
#pragma unroll
    for (int i = 0; i < 4; ++i)
#pragma unroll
      for (int ks = 0; ks < 2; ++ks)
        a[u][i][ks] = Xf4[((size_t)(m16b + i) * 128 + kt * 2 + ks) * 64 + lane];
#pragma unroll
    for (int j = 0; j < 2; ++j)
      b[u][j] = (unsigned)Bf[((n16b + j) * 64 + kt) * 64 + lane];
  };

  auto COMP = [&](int u) {
#pragma unroll
    for (int j = 0; j < 2; ++j)
#pragma unroll
      for (int ks = 0; ks < 2; ++ks) {
        unsigned byte = (b[u][j] >> (ks * 8)) & 0xFFu;
        union { unsigned u32[4]; bf16x8_t v; } ex;
#pragma unroll
        for (int p = 0; p < 4; ++p) {
          unsigned tt = (byte >> (2 * p)) & 3u;
          ex.u32[p] = ((tt | (tt << 15)) & 0x10001u) * 0x3F80u;
        }
#pragma unroll
        for (int i = 0; i < 4; ++i) {
          union { uint4 q; bf16x8_t v; } av;
          av.q = a[u][i][ks];
          acc[i][j] = __builtin_amdgcn_mfma_f32_16x16x32_bf16(av.v, ex.v, acc[i][j], 0, 0, 0);
        }
      }
  };

  LOAD(0, 0);
  for (int ktl = 0; ktl < 32; ktl += 2) {
    LOAD(1, ktl + 1);
    COMP(0);
    if (ktl + 2 < 32) LOAD(0, ktl + 2);
    COMP(1);
  }

  // ---- pairwise K reduction through LDS (contiguous 16B/lane: full-BW) ----
  if (kh == 1) {
#pragma unroll
    for (int i = 0; i < 4; ++i)
#pragma unroll
      for (int j = 0; j < 2; ++j)
        red[wsub][i * 2 + j][lane] = acc[i][j];
  }
  __syncthreads();
  if (kh == 0) {
#pragma unroll
    for (int i = 0; i < 4; ++i)
#pragma unroll
      for (int j = 0; j < 2; ++j)
        acc[i][j] += red[wsub][i * 2 + j][lane];

    // epilogue: C/D layout col = lane&15, row = quad*4 + reg (v1 verbatim)
#pragma unroll
    for (int j = 0; j < 2; ++j) {
      const int n = n0 + wn + j * 16 + l16;
      const float s = rintf(fmaxf(sf[n], 1.0f));
#pragma unroll
      for (int i = 0; i < 4; ++i) {
        const int mr = m0 + i * 16 + quad * 4;
#pragma unroll
        for (int r = 0; r < 4; ++r)
          C[(size_t)(mr + r) * NOUT + n] = acc[i][j][r] * s;
      }
    }
  }
}

extern "C" void kernel_launch(void* const* d_in, const int* in_sizes, int n_in,
                              void* d_out, int out_size, void* d_ws, size_t ws_size,
                              hipStream_t stream) {
  const float* x  = (const float*)d_in[0];  // [1024][4096]
  const float* w  = (const float*)d_in[1];  // [4096][4096]
  const float* sf = (const float*)d_in[2];  // [4096]
  float* out = (float*)d_out;               // [1024][4096]

  unsigned short* Bfrag = (unsigned short*)d_ws;                        // 2 MB
  unsigned short* Xfrag = (unsigned short*)((char*)d_ws + (4u << 20));  // 8 MB

  prep_wx<<<6144, 256, 0, stream>>>((const float4*)w, Bfrag, (const float4*)x,
                                    (uint4*)Xfrag);
  gemm_bin_kernel<<<512, 512, 0, stream>>>(Xfrag, Bfrag, sf, out);
}